// Round 6
// baseline (169.143 us; speedup 1.0000x reference)
//
#include <hip/hip_runtime.h>
#include <hip/hip_bf16.h>

// Problem: B=16384, J=12, Q=7, O=5, H1=H2=128.  Output: fp32 [B,Q,O].
#define B_TOT 16384
#define NQ 7
#define NO 5

typedef float v2f __attribute__((ext_vector_type(2)));

// Workspace layout (float indices)
//  W2F : [12][32 kg][64 hp][4 k4][2] fp32, combined W2+W2a rows i'=1..128
//        lane hp reads 8 consecutive floats per kg (2x dwordx4)
//  W2B : [12][128] fp32 combined bias row (i'=0)
//  W1C : [12][7][6][128] fp32 combined layer-1 weights (natural)
//  VCP : [12][7][64][12] fp32: lane l's 10 V-weights (rows 1+2l, 2+2l) + 2 pad
//  VCB : [12][7][5] fp32 V bias row (i'=0)
#define WS_W2F  0
#define WS_W2B  (WS_W2F + 196608)
#define WS_W1C  (WS_W2B + 1536)
#define WS_VCP  (WS_W1C + 64512)
#define WS_VCB  (WS_VCP + 64512)
#define WS_FLAG_BF16 (WS_VCB + 420)
#define WS_FLAG_J64  (WS_FLAG_BF16 + 1)
#define WS_TOT_FLOATS (WS_FLAG_J64 + 1)
#define WS_NEEDED_BYTES ((size_t)WS_TOT_FLOATS * 4)

// combine index ranges
#define CN0 196608                 // W2F fp32
#define CN1 (CN0 + 1536)           // W2B
#define CN2 (CN1 + 64512)          // W1C
#define CN3 (CN2 + 64512)          // VCP
#define CN4 (CN3 + 420)            // VCB
#define C_TOTAL CN4

// ---------- helpers ----------
__device__ __forceinline__ float ldf(const float* p) { return *p; }
__device__ __forceinline__ float ldf(const __hip_bfloat16* p) {
    return __bfloat162float(*p);
}
__device__ __forceinline__ float sigmoidf_(float v) {
    return 1.0f / (1.0f + __expf(-v));
}
__device__ __forceinline__ v2f splat2(float s) { v2f r; r.x = s; r.y = s; return r; }
// DPP wave64 sum -> lane 63 (row_shr 1,2,4,8; row_bcast15; row_bcast31)
#define DPP_ADD_STEP(v, ctrl) \
    v += __int_as_float(__builtin_amdgcn_update_dpp(0, __float_as_int(v), ctrl, 0xf, 0xf, true))
__device__ __forceinline__ float wave_sum_bcast(float v) {
    DPP_ADD_STEP(v, 0x111);
    DPP_ADD_STEP(v, 0x112);
    DPP_ADD_STEP(v, 0x114);
    DPP_ADD_STEP(v, 0x118);
    DPP_ADD_STEP(v, 0x142);
    DPP_ADD_STEP(v, 0x143);
    return __int_as_float(__builtin_amdgcn_readlane(__float_as_int(v), 63));
}

// ---------- dtype probes ----------
__device__ __forceinline__ int probe_is_bf16(const unsigned int* w1bits) {
    int hits = 0;
    for (int t = 0; t < 64; ++t) {
        unsigned int lo = w1bits[t] & 0xFFFFu;
        unsigned int e = (lo >> 7) & 0xFFu;
        if (lo == 0u || (e >= 100u && e <= 130u)) ++hits;
    }
    return hits >= 32;
}
__device__ __forceinline__ int probe_is_j64(const int* jid) {
    int o = 0;
    for (int t = 0; t < 64; ++t) o |= jid[2*t + 1];
    return (o == 0) ? 1 : 0;
}

// Tiny kernel: run probes ONCE (was: per-thread in combine -> ~17M redundant loads)
__global__ __launch_bounds__(64) void probe_kernel(
    const unsigned int* w1bits, const int* jid, float* ws)
{
    if (threadIdx.x == 0) {
        ((int*)ws)[WS_FLAG_BF16] = probe_is_bf16(w1bits);
        ((int*)ws)[WS_FLAG_J64]  = probe_is_j64(jid);
    }
}

// ---------- weight combine ----------
template<typename T>
__device__ __forceinline__ void combine_body(
    int idx, const T* W1, const T* W1a, const T* W2, const T* W2a,
    const T* V, const T* Va, float* ws)
{
    if (idx < CN0) {
        // fp32 idx -> [j][kg][hp][k4][odd]
        int j = idx >> 14, r = idx & 16383;
        int kg = r >> 9, r2 = r & 511;
        int hp = r2 >> 3, c = r2 & 7;
        int k4 = c >> 1, odd = c & 1;
        int k = kg*4 + k4, i = k + 1, h = hp*2 + odd;
        ws[WS_W2F + idx] = ldf(W2 + i*128 + h) + ldf(W2a + (j*129 + i)*128 + h);
    } else if (idx < CN1) {
        int t = idx - CN0;
        int j = t >> 7, h = t & 127;
        ws[WS_W2B + t] = ldf(W2 + h) + ldf(W2a + j*129*128 + h);
    } else if (idx < CN2) {
        int t = idx - CN1;
        int j = t / 5376;  int r = t - j*5376;
        ws[WS_W1C + t] = ldf(W1 + r) + ldf(W1a + j*5376 + r);
    } else if (idx < CN3) {
        int t = idx - CN2;
        int j = t / 5376;  int r = t - j*5376;
        int q = r / 768;   int r2 = r - q*768;
        int ln = r2 / 12;  int c = r2 - ln*12;
        float v = 0.0f;
        if (c < 10) {
            int src = q*645 + 5 + 10*ln + c;
            v = ldf(V + src) + ldf(Va + j*4515 + src);
        }
        ws[WS_VCP + t] = v;
    } else if (idx < CN4) {
        int t = idx - CN3;
        int j = t / 35;  int r = t - j*35;
        int q = r / 5,   o = r - q*5;
        int src = q*645 + o;
        ws[WS_VCB + t] = ldf(V + src) + ldf(Va + j*4515 + src);
    }
}

__global__ __launch_bounds__(256) void combine_kernel(
    const void* W1, const void* W1a, const void* W2, const void* W2a,
    const void* V,  const void* Va, float* ws)
{
    const int isb = ((const int*)ws)[WS_FLAG_BF16];   // uniform -> s_load
    int idx = blockIdx.x * 256 + threadIdx.x;
    if (idx >= C_TOTAL) return;
    if (isb) combine_body(idx,
        (const __hip_bfloat16*)W1, (const __hip_bfloat16*)W1a,
        (const __hip_bfloat16*)W2, (const __hip_bfloat16*)W2a,
        (const __hip_bfloat16*)V,  (const __hip_bfloat16*)Va, ws);
    else combine_body(idx,
        (const float*)W1, (const float*)W1a, (const float*)W2,
        (const float*)W2a, (const float*)V, (const float*)Va, ws);
}

// ---------- main kernel ----------
// One wave per b; block = 4 waves = 4 b's. Grid = 4096; 8 blocks/CU resident.
__global__ __launch_bounds__(256, 8) void CalibrationNetwork_81329500717524_kernel(
    const void* xraw, const int* __restrict__ jid,
    const float* __restrict__ ws, float* __restrict__ out)
{
    __shared__ __align__(16) float lds_z1[4][NQ][128];   // 14336 B
    const int tid = threadIdx.x;
    const int l = tid & 63, w = tid >> 6;
    const int isb = ((const int*)ws)[WS_FLAG_BF16];
    const int j64 = ((const int*)ws)[WS_FLAG_J64];

    const int b  = blockIdx.x * 4 + w;
    const int bu = __builtin_amdgcn_readfirstlane(b);
    const int ju = __builtin_amdgcn_readfirstlane(j64 ? jid[2*bu] : jid[bu]);

    // ---- x[b]: wave-uniform -> scalar loads ----
    float xs[35];
    if (isb) {
        const __hip_bfloat16* xp = (const __hip_bfloat16*)xraw + bu*35;
        #pragma unroll
        for (int i = 0; i < 35; ++i) xs[i] = ldf(xp + i);
    } else {
        const float* xp = (const float*)xraw + bu*35;
        #pragma unroll
        for (int i = 0; i < 35; ++i) xs[i] = xp[i];
    }

    // ---- layer 1: lane l owns h = 2l, 2l+1 (pk_fma) ----
    const float* W1cj = ws + WS_W1C + ju*5376;
    #pragma unroll
    for (int q = 0; q < NQ; ++q) {
        const float* Wq = W1cj + q*768;
        v2f a = *(const v2f*)(Wq + 2*l);                  // bias row i'=0
        #pragma unroll
        for (int i = 1; i <= 5; ++i) {
            v2f wv = *(const v2f*)(Wq + i*128 + 2*l);
            a = __builtin_elementwise_fma(wv, splat2(xs[q*5 + i - 1]), a);
        }
        v2f zv; zv.x = sigmoidf_(a.x); zv.y = sigmoidf_(a.y);
        *(v2f*)(&lds_z1[w][q][2*l]) = zv;
    }
    __syncthreads();

    // ---- layer 2: lane l owns h' = 2l, 2l+1; 8 fp32 weights per kg ----
    const float* W2p = ws + WS_W2F + ju*16384 + l*8;
    v2f acc[NQ];
    {
        const v2f bias = *(const v2f*)(ws + WS_W2B + ju*128 + 2*l);
        #pragma unroll
        for (int q = 0; q < NQ; ++q) acc[q] = bias;
    }
    #pragma unroll 2
    for (int kg = 0; kg < 32; ++kg) {
        const float4 wa = *(const float4*)(W2p + kg*512);      // k4=0,1
        const float4 wb = *(const float4*)(W2p + kg*512 + 4);  // k4=2,3
        v2f w0, w1, w2, w3;
        w0.x = wa.x; w0.y = wa.y;  w1.x = wa.z; w1.y = wa.w;
        w2.x = wb.x; w2.y = wb.y;  w3.x = wb.z; w3.y = wb.w;
        #pragma unroll
        for (int q = 0; q < NQ; ++q) {
            const float4 z = *(const float4*)(&lds_z1[w][q][kg*4]);  // broadcast
            acc[q] = __builtin_elementwise_fma(w0, splat2(z.x), acc[q]);
            acc[q] = __builtin_elementwise_fma(w1, splat2(z.y), acc[q]);
            acc[q] = __builtin_elementwise_fma(w2, splat2(z.z), acc[q]);
            acc[q] = __builtin_elementwise_fma(w3, splat2(z.w), acc[q]);
        }
    }

    // ---- output layer + softmax (DPP reduction + readlane) ----
    float res = 0.0f;
    #pragma unroll 1
    for (int q = 0; q < NQ; ++q) {
        const float zA = sigmoidf_(acc[q].x);   // z2[2l]
        const float zB = sigmoidf_(acc[q].y);   // z2[2l+1]
        const float* vp = ws + WS_VCP + ((ju*NQ + q)*64 + l)*12;
        const float4 v0 = *(const float4*)(vp);
        const float4 v1 = *(const float4*)(vp + 4);
        const float2 v2 = *(const float2*)(vp + 8);
        float p0 = wave_sum_bcast(zA*v0.x + zB*v1.y);
        float p1 = wave_sum_bcast(zA*v0.y + zB*v1.z);
        float p2 = wave_sum_bcast(zA*v0.z + zB*v1.w);
        float p3 = wave_sum_bcast(zA*v0.w + zB*v2.x);
        float p4 = wave_sum_bcast(zA*v1.x + zB*v2.y);
        const float* vb = ws + WS_VCB + (ju*NQ + q)*5;
        p0 += vb[0]; p1 += vb[1]; p2 += vb[2]; p3 += vb[3]; p4 += vb[4];
        float m = fmaxf(fmaxf(fmaxf(p0, p1), fmaxf(p2, p3)), p4);
        float e0 = __expf(p0 - m), e1 = __expf(p1 - m), e2 = __expf(p2 - m),
              e3 = __expf(p3 - m), e4 = __expf(p4 - m);
        float inv = 1.0f / (e0 + e1 + e2 + e3 + e4);
        int o = l - q*5;
        if (o >= 0 && o < 5) {
            float v = (o == 0) ? e0 : (o == 1) ? e1 : (o == 2) ? e2
                    : (o == 3) ? e3 : e4;
            res = v * inv;
        }
    }
    if (l < 35) out[b*35 + l] = res;
}

// ---------- fallback path B: no workspace ----------
template<typename T>
__device__ void direct_body(
    const T* __restrict__ x, const int* __restrict__ jid, int j64,
    const T* __restrict__ W1, const T* __restrict__ W1a,
    const T* __restrict__ W2, const T* __restrict__ W2a,
    const T* __restrict__ V,  const T* __restrict__ Va,
    float* __restrict__ out, float (*lds_z1)[NQ][128])
{
    const int tid = threadIdx.x;
    const int l = tid & 63, w = tid >> 6;

    #pragma unroll 1
    for (int t = 0; t < 4; ++t) {
        const int b = blockIdx.x * 16 + w * 4 + t;
        const int j = j64 ? jid[2*b] : jid[b];

        float xv = 0.0f;
        if (l < 35) xv = ldf(x + b*35 + l);

        #pragma unroll
        for (int q = 0; q < NQ; ++q) {
            const T* Wq  = W1  + q*768;
            const T* Waq = W1a + j*5376 + q*768;
            float a  = ldf(Wq + l)      + ldf(Waq + l);
            float bb = ldf(Wq + 64 + l) + ldf(Waq + 64 + l);
            #pragma unroll
            for (int i = 1; i <= 5; ++i) {
                float xi = __shfl(xv, q*5 + (i - 1), 64);
                a  = fmaf(xi, ldf(Wq + i*128 + l)      + ldf(Waq + i*128 + l),      a);
                bb = fmaf(xi, ldf(Wq + i*128 + 64 + l) + ldf(Waq + i*128 + 64 + l), bb);
            }
            lds_z1[w][q][l]      = sigmoidf_(a);
            lds_z1[w][q][64 + l] = sigmoidf_(bb);
        }
        __syncthreads();

        float accA[NQ], accB[NQ];
        {
            const float biasA = ldf(W2 + l)      + ldf(W2a + j*129*128 + l);
            const float biasB = ldf(W2 + 64 + l) + ldf(W2a + j*129*128 + 64 + l);
            #pragma unroll
            for (int q = 0; q < NQ; ++q) { accA[q] = biasA; accB[q] = biasB; }
        }
        #pragma unroll 1
        for (int k = 0; k < 128; ++k) {
            const int i = k + 1;
            const float wA = ldf(W2 + i*128 + l)      + ldf(W2a + (j*129 + i)*128 + l);
            const float wB = ldf(W2 + i*128 + 64 + l) + ldf(W2a + (j*129 + i)*128 + 64 + l);
            #pragma unroll
            for (int q = 0; q < NQ; ++q) {
                const float z = lds_z1[w][q][k];
                accA[q] = fmaf(wA, z, accA[q]);
                accB[q] = fmaf(wB, z, accB[q]);
            }
        }
        __syncthreads();

        #pragma unroll 1
        for (int q = 0; q < NQ; ++q) {
            const float zA = sigmoidf_(accA[q]);
            const float zB = sigmoidf_(accB[q]);
            const T* Vq  = V  + q*645;
            const T* Vaq = Va + j*4515 + q*645;
            float p[NO];
            #pragma unroll
            for (int o = 0; o < NO; ++o) {
                float vA = ldf(Vq + (1 + l)*5 + o)  + ldf(Vaq + (1 + l)*5 + o);
                float vB = ldf(Vq + (65 + l)*5 + o) + ldf(Vaq + (65 + l)*5 + o);
                p[o] = zA*vA + zB*vB;
            }
            #pragma unroll
            for (int off = 32; off > 0; off >>= 1) {
                #pragma unroll
                for (int o = 0; o < NO; ++o) p[o] += __shfl_xor(p[o], off, 64);
            }
            #pragma unroll
            for (int o = 0; o < NO; ++o) p[o] += ldf(Vq + o) + ldf(Vaq + o);
            float m = fmaxf(fmaxf(fmaxf(p[0], p[1]), fmaxf(p[2], p[3])), p[4]);
            float e[NO], s = 0.0f;
            #pragma unroll
            for (int o = 0; o < NO; ++o) { e[o] = __expf(p[o] - m); s += e[o]; }
            float inv = 1.0f / s;
            if (l < 5) out[b*35 + q*5 + l] = e[l] * inv;
        }
    }
}

__global__ __launch_bounds__(256) void calib_direct_kernel(
    const void* x, const int* jid,
    const void* W1, const void* W1a, const void* W2, const void* W2a,
    const void* V,  const void* Va, float* out)
{
    __shared__ __align__(16) float lds_z1[4][NQ][128];
    const int isb = probe_is_bf16((const unsigned int*)W1);
    const int j64 = probe_is_j64(jid);
    if (isb) direct_body(
        (const __hip_bfloat16*)x, jid, j64,
        (const __hip_bfloat16*)W1, (const __hip_bfloat16*)W1a,
        (const __hip_bfloat16*)W2, (const __hip_bfloat16*)W2a,
        (const __hip_bfloat16*)V,  (const __hip_bfloat16*)Va, out, lds_z1);
    else direct_body(
        (const float*)x, jid, j64,
        (const float*)W1, (const float*)W1a, (const float*)W2,
        (const float*)W2a, (const float*)V, (const float*)Va, out, lds_z1);
}

extern "C" void kernel_launch(void* const* d_in, const int* in_sizes, int n_in,
                              void* d_out, int out_size, void* d_ws, size_t ws_size,
                              hipStream_t stream)
{
    const void* x   = d_in[0];
    const int*  jid = (const int*)d_in[1];
    const void* W1  = d_in[2];
    const void* W1a = d_in[3];
    const void* W2  = d_in[4];
    const void* W2a = d_in[5];
    const void* V   = d_in[6];
    const void* Va  = d_in[7];
    float* out = (float*)d_out;

    if (ws_size >= WS_NEEDED_BYTES) {
        float* ws = (float*)d_ws;
        probe_kernel<<<1, 64, 0, stream>>>((const unsigned int*)W1, jid, ws);
        combine_kernel<<<(C_TOTAL + 255) / 256, 256, 0, stream>>>(
            W1, W1a, W2, W2a, V, Va, ws);
        CalibrationNetwork_81329500717524_kernel<<<B_TOT / 4, 256, 0, stream>>>(
            x, jid, ws, out);
    } else {
        calib_direct_kernel<<<B_TOT / 16, 256, 0, stream>>>(
            x, jid, W1, W1a, W2, W2a, V, Va, out);
    }
}

// Round 7
// 145.958 us; speedup vs baseline: 1.1588x; 1.1588x over previous
//
#include <hip/hip_runtime.h>
#include <hip/hip_bf16.h>

// Problem: B=16384, J=12, Q=7, O=5, H1=H2=128.  Output: fp32 [B,Q,O].
#define B_TOT 16384
#define NQ 7
#define NO 5

typedef float v2f __attribute__((ext_vector_type(2)));
typedef _Float16 v2h __attribute__((ext_vector_type(2)));

// Workspace layout (float-slot indices)
//  W2H : [12][16 kqg][64 l][8 u] uints; u: [hp 2][kp 2] f16 k-pair
//        (h'=2l+hp, k = kqg*8 + kp*2 + {0,1}; i' = k+1), combined W2+W2a
//  W2B : [12][128] fp32 combined bias row (i'=0)
//  W1C : [12][7][6][128] fp32 combined layer-1 weights (natural)
//  VCP : [12][7][64][12] fp32: lane l's 10 V-weights (rows 1+2l, 2+2l) + 2 pad
//  VCB : [12][7][5] fp32 V bias row (i'=0)
#define WS_W2H  0
#define WS_W2B  (WS_W2H + 98304)
#define WS_W1C  (WS_W2B + 1536)
#define WS_VCP  (WS_W1C + 64512)
#define WS_VCB  (WS_VCP + 64512)
#define WS_FLAG_BF16 (WS_VCB + 420)
#define WS_FLAG_J64  (WS_FLAG_BF16 + 1)
#define WS_TOT_FLOATS (WS_FLAG_J64 + 1)
#define WS_NEEDED_BYTES ((size_t)WS_TOT_FLOATS * 4)

// combine index ranges
#define CN0 98304                  // W2H uints
#define CN1 (CN0 + 1536)           // W2B
#define CN2 (CN1 + 64512)          // W1C
#define CN3 (CN2 + 64512)          // VCP
#define CN4 (CN3 + 420)            // VCB
#define C_TOTAL CN4

// ---------- helpers ----------
__device__ __forceinline__ float ldf(const float* p) { return *p; }
__device__ __forceinline__ float ldf(const __hip_bfloat16* p) {
    return __bfloat162float(*p);
}
__device__ __forceinline__ float sigmoidf_(float v) {
    return 1.0f / (1.0f + __expf(-v));
}
__device__ __forceinline__ v2f splat2(float s) { v2f r; r.x = s; r.y = s; return r; }
__device__ __forceinline__ v2h u2h(unsigned int u) {
    return __builtin_bit_cast(v2h, u);
}
__device__ __forceinline__ unsigned int h2u(float a, float b) {
    unsigned short ua = __builtin_bit_cast(unsigned short, (_Float16)a);
    unsigned short ub = __builtin_bit_cast(unsigned short, (_Float16)b);
    return (unsigned int)ua | ((unsigned int)ub << 16);
}
__device__ __forceinline__ float fdot2_(unsigned int wu, unsigned int zu, float c) {
#if __has_builtin(__builtin_amdgcn_fdot2)
    return __builtin_amdgcn_fdot2(u2h(wu), u2h(zu), c, false);
#else
    v2h wv = u2h(wu), zv = u2h(zu);
    c = fmaf((float)wv.x, (float)zv.x, c);
    return fmaf((float)wv.y, (float)zv.y, c);
#endif
}
// DPP wave64 sum -> broadcast via readlane 63
#define DPP_ADD_STEP(v, ctrl) \
    v += __int_as_float(__builtin_amdgcn_update_dpp(0, __float_as_int(v), ctrl, 0xf, 0xf, true))
__device__ __forceinline__ float wave_sum_bcast(float v) {
    DPP_ADD_STEP(v, 0x111);
    DPP_ADD_STEP(v, 0x112);
    DPP_ADD_STEP(v, 0x114);
    DPP_ADD_STEP(v, 0x118);
    DPP_ADD_STEP(v, 0x142);
    DPP_ADD_STEP(v, 0x143);
    return __int_as_float(__builtin_amdgcn_readlane(__float_as_int(v), 63));
}

// ---------- dtype probes (fallback path only) ----------
__device__ __forceinline__ int probe_is_bf16(const unsigned int* w1bits) {
    int hits = 0;
    for (int t = 0; t < 64; ++t) {
        unsigned int lo = w1bits[t] & 0xFFFFu;
        unsigned int e = (lo >> 7) & 0xFFu;
        if (lo == 0u || (e >= 100u && e <= 130u)) ++hits;
    }
    return hits >= 32;
}
__device__ __forceinline__ int probe_is_j64(const int* jid) {
    int o = 0;
    for (int t = 0; t < 64; ++t) o |= jid[2*t + 1];
    return (o == 0) ? 1 : 0;
}

// ---------- weight combine ----------
template<typename T>
__device__ __forceinline__ void combine_body(
    int idx, const T* W1, const T* W1a, const T* W2, const T* W2a,
    const T* V, const T* Va, float* ws)
{
    if (idx < CN0) {
        // uint idx -> [j][kqg][l][u], u = hp*4 + kp
        int j = idx >> 13, r = idx & 8191;
        int kqg = r >> 9, r2 = r & 511;
        int l = r2 >> 3, u = r2 & 7;
        int h = 2*l + (u >> 2);
        int k0 = kqg*8 + (u & 3)*2;
        int i0 = k0 + 1, i1 = k0 + 2;
        float w0 = ldf(W2 + i0*128 + h) + ldf(W2a + (j*129 + i0)*128 + h);
        float w1 = ldf(W2 + i1*128 + h) + ldf(W2a + (j*129 + i1)*128 + h);
        ((unsigned int*)(ws + WS_W2H))[idx] = h2u(w0, w1);
    } else if (idx < CN1) {
        int t = idx - CN0;
        int j = t >> 7, h = t & 127;
        ws[WS_W2B + t] = ldf(W2 + h) + ldf(W2a + j*129*128 + h);
    } else if (idx < CN2) {
        int t = idx - CN1;
        int j = t / 5376;  int r = t - j*5376;
        ws[WS_W1C + t] = ldf(W1 + r) + ldf(W1a + j*5376 + r);
    } else if (idx < CN3) {
        int t = idx - CN2;
        int j = t / 5376;  int r = t - j*5376;
        int q = r / 768;   int r2 = r - q*768;
        int ln = r2 / 12;  int c = r2 - ln*12;
        float v = 0.0f;
        if (c < 10) {
            int src = q*645 + 5 + 10*ln + c;
            v = ldf(V + src) + ldf(Va + j*4515 + src);
        }
        ws[WS_VCP + t] = v;
    } else if (idx < CN4) {
        int t = idx - CN3;
        int j = t / 35;  int r = t - j*35;
        int q = r / 5,   o = r - q*5;
        int src = q*645 + o;
        ws[WS_VCB + t] = ldf(V + src) + ldf(Va + j*4515 + src);
    }
}

__global__ __launch_bounds__(256) void combine_kernel(
    const void* W1, const void* W1a, const void* W2, const void* W2a,
    const void* V,  const void* Va,  const int* jid, float* ws)
{
    // parallel in-block probe (wave 0, 1-2 loads/lane + ballot)
    __shared__ int shf[2];
    const int tid = threadIdx.x;
    if (tid < 64) {
        unsigned int wbits = ((const unsigned int*)W1)[tid];
        unsigned int lo = wbits & 0xFFFFu;
        unsigned int e = (lo >> 7) & 0xFFu;
        unsigned long long mb = __ballot(lo == 0u || (e >= 100u && e <= 130u));
        unsigned long long mo = __ballot(jid[2*tid + 1] != 0);
        if (tid == 0) {
            int isb = (__popcll(mb) >= 32);
            int j64 = (mo == 0ULL);
            shf[0] = isb; shf[1] = j64;
            if (blockIdx.x == 0) {
                ((int*)ws)[WS_FLAG_BF16] = isb;
                ((int*)ws)[WS_FLAG_J64]  = j64;
            }
        }
    }
    __syncthreads();
    const int isb = shf[0];

    int idx = blockIdx.x * 256 + tid;
    if (idx >= C_TOTAL) return;
    if (isb) combine_body(idx,
        (const __hip_bfloat16*)W1, (const __hip_bfloat16*)W1a,
        (const __hip_bfloat16*)W2, (const __hip_bfloat16*)W2a,
        (const __hip_bfloat16*)V,  (const __hip_bfloat16*)Va, ws);
    else combine_body(idx,
        (const float*)W1, (const float*)W1a, (const float*)W2,
        (const float*)W2a, (const float*)V, (const float*)Va, ws);
}

// ---------- main kernel ----------
// One wave per b; block = 4 waves = 4 b's. Grid = 4096; 8 blocks/CU resident.
// No __syncthreads: lds_z slices are wave-private (DS ops in-order per wave).
__global__ __launch_bounds__(256, 8) void CalibrationNetwork_81329500717524_kernel(
    const void* xraw, const int* __restrict__ jid,
    const float* __restrict__ ws, float* __restrict__ out)
{
    __shared__ __align__(16) unsigned int lds_z[4][NQ][64];   // f16 pairs, 7 KB
    const int tid = threadIdx.x;
    const int l = tid & 63, w = tid >> 6;
    const int isb = ((const int*)ws)[WS_FLAG_BF16];
    const int j64 = ((const int*)ws)[WS_FLAG_J64];

    const int b  = blockIdx.x * 4 + w;
    const int bu = __builtin_amdgcn_readfirstlane(b);
    const int ju = __builtin_amdgcn_readfirstlane(j64 ? jid[2*bu] : jid[bu]);

    // ---- x[b]: wave-uniform -> scalar loads ----
    float xs[35];
    if (isb) {
        const __hip_bfloat16* xp = (const __hip_bfloat16*)xraw + bu*35;
        #pragma unroll
        for (int i = 0; i < 35; ++i) xs[i] = ldf(xp + i);
    } else {
        const float* xp = (const float*)xraw + bu*35;
        #pragma unroll
        for (int i = 0; i < 35; ++i) xs[i] = xp[i];
    }

    // ---- layer 1: lane l owns h = 2l, 2l+1; store z1 as packed f16 pair ----
    const float* W1cj = ws + WS_W1C + ju*5376;
    #pragma unroll
    for (int q = 0; q < NQ; ++q) {
        const float* Wq = W1cj + q*768;
        v2f a = *(const v2f*)(Wq + 2*l);                  // bias row i'=0
        #pragma unroll
        for (int i = 1; i <= 5; ++i) {
            v2f wv = *(const v2f*)(Wq + i*128 + 2*l);
            a = __builtin_elementwise_fma(wv, splat2(xs[q*5 + i - 1]), a);
        }
        lds_z[w][q][l] = h2u(sigmoidf_(a.x), sigmoidf_(a.y));
    }

    // ---- layer 2: lane l owns h' = 2l, 2l+1; f16 dot2, 8 k's per kqg ----
    const unsigned int* W2p = (const unsigned int*)(ws + WS_W2H) + ju*8192 + l*8;
    float accA[NQ], accB[NQ];
    {
        const v2f bias = *(const v2f*)(ws + WS_W2B + ju*128 + 2*l);
        #pragma unroll
        for (int q = 0; q < NQ; ++q) { accA[q] = bias.x; accB[q] = bias.y; }
    }
    #pragma unroll 2
    for (int kqg = 0; kqg < 16; ++kqg) {
        const uint4 wa = *(const uint4*)(W2p + kqg*512);      // h'=2l,   kp 0..3
        const uint4 wb = *(const uint4*)(W2p + kqg*512 + 4);  // h'=2l+1, kp 0..3
        #pragma unroll
        for (int q = 0; q < NQ; ++q) {
            const uint4 z4 = *(const uint4*)(&lds_z[w][q][kqg*4]);  // broadcast
            accA[q] = fdot2_(wa.x, z4.x, accA[q]);
            accA[q] = fdot2_(wa.y, z4.y, accA[q]);
            accA[q] = fdot2_(wa.z, z4.z, accA[q]);
            accA[q] = fdot2_(wa.w, z4.w, accA[q]);
            accB[q] = fdot2_(wb.x, z4.x, accB[q]);
            accB[q] = fdot2_(wb.y, z4.y, accB[q]);
            accB[q] = fdot2_(wb.z, z4.z, accB[q]);
            accB[q] = fdot2_(wb.w, z4.w, accB[q]);
        }
    }

    // ---- output layer + softmax (DPP reduction + readlane) ----
    float res = 0.0f;
    #pragma unroll 1
    for (int q = 0; q < NQ; ++q) {
        const float zA = sigmoidf_(accA[q]);   // z2[2l]
        const float zB = sigmoidf_(accB[q]);   // z2[2l+1]
        const float* vp = ws + WS_VCP + ((ju*NQ + q)*64 + l)*12;
        const float4 v0 = *(const float4*)(vp);
        const float4 v1 = *(const float4*)(vp + 4);
        const float2 v2 = *(const float2*)(vp + 8);
        float p0 = wave_sum_bcast(zA*v0.x + zB*v1.y);
        float p1 = wave_sum_bcast(zA*v0.y + zB*v1.z);
        float p2 = wave_sum_bcast(zA*v0.z + zB*v1.w);
        float p3 = wave_sum_bcast(zA*v0.w + zB*v2.x);
        float p4 = wave_sum_bcast(zA*v1.x + zB*v2.y);
        const float* vb = ws + WS_VCB + (ju*NQ + q)*5;
        p0 += vb[0]; p1 += vb[1]; p2 += vb[2]; p3 += vb[3]; p4 += vb[4];
        float m = fmaxf(fmaxf(fmaxf(p0, p1), fmaxf(p2, p3)), p4);
        float e0 = __expf(p0 - m), e1 = __expf(p1 - m), e2 = __expf(p2 - m),
              e3 = __expf(p3 - m), e4 = __expf(p4 - m);
        float inv = 1.0f / (e0 + e1 + e2 + e3 + e4);
        int o = l - q*5;
        if (o >= 0 && o < 5) {
            float v = (o == 0) ? e0 : (o == 1) ? e1 : (o == 2) ? e2
                    : (o == 3) ? e3 : e4;
            res = v * inv;
        }
    }
    if (l < 35) out[b*35 + l] = res;
}

// ---------- fallback path B: no workspace ----------
template<typename T>
__device__ void direct_body(
    const T* __restrict__ x, const int* __restrict__ jid, int j64,
    const T* __restrict__ W1, const T* __restrict__ W1a,
    const T* __restrict__ W2, const T* __restrict__ W2a,
    const T* __restrict__ V,  const T* __restrict__ Va,
    float* __restrict__ out, float (*lds_z1)[NQ][128])
{
    const int tid = threadIdx.x;
    const int l = tid & 63, w = tid >> 6;

    #pragma unroll 1
    for (int t = 0; t < 4; ++t) {
        const int b = blockIdx.x * 16 + w * 4 + t;
        const int j = j64 ? jid[2*b] : jid[b];

        float xv = 0.0f;
        if (l < 35) xv = ldf(x + b*35 + l);

        #pragma unroll
        for (int q = 0; q < NQ; ++q) {
            const T* Wq  = W1  + q*768;
            const T* Waq = W1a + j*5376 + q*768;
            float a  = ldf(Wq + l)      + ldf(Waq + l);
            float bb = ldf(Wq + 64 + l) + ldf(Waq + 64 + l);
            #pragma unroll
            for (int i = 1; i <= 5; ++i) {
                float xi = __shfl(xv, q*5 + (i - 1), 64);
                a  = fmaf(xi, ldf(Wq + i*128 + l)      + ldf(Waq + i*128 + l),      a);
                bb = fmaf(xi, ldf(Wq + i*128 + 64 + l) + ldf(Waq + i*128 + 64 + l), bb);
            }
            lds_z1[w][q][l]      = sigmoidf_(a);
            lds_z1[w][q][64 + l] = sigmoidf_(bb);
        }
        __syncthreads();

        float accA[NQ], accB[NQ];
        {
            const float biasA = ldf(W2 + l)      + ldf(W2a + j*129*128 + l);
            const float biasB = ldf(W2 + 64 + l) + ldf(W2a + j*129*128 + 64 + l);
            #pragma unroll
            for (int q = 0; q < NQ; ++q) { accA[q] = biasA; accB[q] = biasB; }
        }
        #pragma unroll 1
        for (int k = 0; k < 128; ++k) {
            const int i = k + 1;
            const float wA = ldf(W2 + i*128 + l)      + ldf(W2a + (j*129 + i)*128 + l);
            const float wB = ldf(W2 + i*128 + 64 + l) + ldf(W2a + (j*129 + i)*128 + 64 + l);
            #pragma unroll
            for (int q = 0; q < NQ; ++q) {
                const float z = lds_z1[w][q][k];
                accA[q] = fmaf(wA, z, accA[q]);
                accB[q] = fmaf(wB, z, accB[q]);
            }
        }
        __syncthreads();

        #pragma unroll 1
        for (int q = 0; q < NQ; ++q) {
            const float zA = sigmoidf_(accA[q]);
            const float zB = sigmoidf_(accB[q]);
            const T* Vq  = V  + q*645;
            const T* Vaq = Va + j*4515 + q*645;
            float p[NO];
            #pragma unroll
            for (int o = 0; o < NO; ++o) {
                float vA = ldf(Vq + (1 + l)*5 + o)  + ldf(Vaq + (1 + l)*5 + o);
                float vB = ldf(Vq + (65 + l)*5 + o) + ldf(Vaq + (65 + l)*5 + o);
                p[o] = zA*vA + zB*vB;
            }
            #pragma unroll
            for (int off = 32; off > 0; off >>= 1) {
                #pragma unroll
                for (int o = 0; o < NO; ++o) p[o] += __shfl_xor(p[o], off, 64);
            }
            #pragma unroll
            for (int o = 0; o < NO; ++o) p[o] += ldf(Vq + o) + ldf(Vaq + o);
            float m = fmaxf(fmaxf(fmaxf(p[0], p[1]), fmaxf(p[2], p[3])), p[4]);
            float e[NO], s = 0.0f;
            #pragma unroll
            for (int o = 0; o < NO; ++o) { e[o] = __expf(p[o] - m); s += e[o]; }
            float inv = 1.0f / s;
            if (l < 5) out[b*35 + q*5 + l] = e[l] * inv;
        }
    }
}

__global__ __launch_bounds__(256) void calib_direct_kernel(
    const void* x, const int* jid,
    const void* W1, const void* W1a, const void* W2, const void* W2a,
    const void* V,  const void* Va, float* out)
{
    __shared__ __align__(16) float lds_z1[4][NQ][128];
    const int isb = probe_is_bf16((const unsigned int*)W1);
    const int j64 = probe_is_j64(jid);
    if (isb) direct_body(
        (const __hip_bfloat16*)x, jid, j64,
        (const __hip_bfloat16*)W1, (const __hip_bfloat16*)W1a,
        (const __hip_bfloat16*)W2, (const __hip_bfloat16*)W2a,
        (const __hip_bfloat16*)V,  (const __hip_bfloat16*)Va, out, lds_z1);
    else direct_body(
        (const float*)x, jid, j64,
        (const float*)W1, (const float*)W1a, (const float*)W2,
        (const float*)W2a, (const float*)V, (const float*)Va, out, lds_z1);
}

extern "C" void kernel_launch(void* const* d_in, const int* in_sizes, int n_in,
                              void* d_out, int out_size, void* d_ws, size_t ws_size,
                              hipStream_t stream)
{
    const void* x   = d_in[0];
    const int*  jid = (const int*)d_in[1];
    const void* W1  = d_in[2];
    const void* W1a = d_in[3];
    const void* W2  = d_in[4];
    const void* W2a = d_in[5];
    const void* V   = d_in[6];
    const void* Va  = d_in[7];
    float* out = (float*)d_out;

    if (ws_size >= WS_NEEDED_BYTES) {
        float* ws = (float*)d_ws;
        combine_kernel<<<(C_TOTAL + 255) / 256, 256, 0, stream>>>(
            W1, W1a, W2, W2a, V, Va, jid, ws);
        CalibrationNetwork_81329500717524_kernel<<<B_TOT / 4, 256, 0, stream>>>(
            x, jid, ws, out);
    } else {
        calib_direct_kernel<<<B_TOT / 16, 256, 0, stream>>>(
            x, jid, W1, W1a, W2, W2a, V, Va, out);
    }
}